// Round 13
// baseline (258.994 us; speedup 1.0000x reference)
//
#include <hip/hip_runtime.h>
#include <hip/hip_fp16.h>
#include <math.h>

#define Bb 8
#define Tt 4
#define Nn 2048
#define Dd 256
#define Mm 4096
#define Ee 8
#define ROWS (Bb*Nn)   // 16384
#define KSEL 8
#define KC 16          // ranking candidates

// output offsets (floats)
#define O_GATE 0LL
#define O_MEMR 131072LL
#define O_LABR 4325376LL
#define O_MLAB 4456448LL
#define O_ATTW 4489216LL

// ws layout (bytes)
#define WS_WT    0LL            // 256 KB fp32 WT
#define WS_KH    262144LL       // 2 MB f16 key
#define WS_CAND  16777216LL     // 16.8 MB u32 cand[16384][32][8]
#define WS_QH    150994944LL    // 8 MB f16 q

typedef float f32x4 __attribute__((ext_vector_type(4)));
typedef short short8 __attribute__((ext_vector_type(8)));
typedef _Float16 f16x8 __attribute__((ext_vector_type(8)));

__device__ __forceinline__ unsigned short f2h(float x) {
    __half h = __float2half(x);
    return *reinterpret_cast<unsigned short*>(&h);
}

__device__ __forceinline__ void gload_lds16(const void* g, void* l) {
    __builtin_amdgcn_global_load_lds(
        (const __attribute__((address_space(1))) unsigned int*)g,
        (__attribute__((address_space(3))) unsigned int*)l,
        16, 0, 0);
}

// ---------------- K0: prep (transpose W | key->f16 | mem_label) ----------------
// grid = 256 + 4096 + 16 = 4368 blocks
__global__ __launch_bounds__(256) void k_prep(const float* __restrict__ W, float* __restrict__ WT,
                                              const float* __restrict__ key, unsigned short* __restrict__ kh,
                                              const float* __restrict__ mem, const float* __restrict__ wg,
                                              float* __restrict__ mlab) {
    int b = blockIdx.x, tid = threadIdx.x;
    if (b < 256) {
        int i = b * 256 + tid;
        int r = i >> 8, c = i & 255;
        WT[c * 256 + r] = W[r * 256 + c];
    } else if (b < 256 + 4096) {
        int idx = (b - 256) * 256 + tid;     // covers all Mm*Dd = 1048576
        kh[idx] = f2h(key[idx]);
    } else {
        int m = (b - 4352) * 256 + tid;
        if (m < Mm) {
            float acc[Ee];
            #pragma unroll
            for (int e = 0; e < Ee; ++e) acc[e] = 0.f;
            const float* mr = mem + (long long)m * Dd;
            for (int d = 0; d < Dd; ++d) {
                float mv = mr[d];
                #pragma unroll
                for (int e = 0; e < Ee; ++e) acc[e] = fmaf(mv, wg[d * Ee + e], acc[e]);
            }
            float mx = acc[0];
            #pragma unroll
            for (int e = 1; e < Ee; ++e) mx = fmaxf(mx, acc[e]);
            float z = 0.f;
            #pragma unroll
            for (int e = 0; e < Ee; ++e) { acc[e] = expf(acc[e] - mx); z += acc[e]; }
            float inv = 1.f / z;
            #pragma unroll
            for (int e = 0; e < Ee; ++e) mlab[(long long)m * Ee + e] = acc[e] * inv;
        }
    }
}

// ---------------- K1: x = mean_T(prop); q = tanh(x @ W^T + b) -> f32 + f16 ----------------
__global__ __launch_bounds__(256) void k_q(const float* __restrict__ prop,
                                           const float* __restrict__ WT,
                                           const float* __restrict__ bias,
                                           float* __restrict__ qf,
                                           unsigned short* __restrict__ qh) {
    __shared__ __align__(16) float xs[16][256];
    int tid = threadIdx.x;
    int row0 = blockIdx.x * 16;
    #pragma unroll
    for (int pass = 0; pass < 4; ++pass) {
        int r = pass * 4 + (tid >> 6);
        int d4 = tid & 63;
        int row = row0 + r;
        int b = row >> 11;
        int n = row & 2047;
        const float4* p = (const float4*)(prop + ((long long)(b * Tt) * Nn + n) * Dd) + d4;
        float4 s = make_float4(0.f, 0.f, 0.f, 0.f);
        #pragma unroll
        for (int t = 0; t < Tt; ++t) {
            float4 v = p[(long long)t * Nn * Dd / 4];
            s.x += v.x; s.y += v.y; s.z += v.z; s.w += v.w;
        }
        xs[r][d4 * 4 + 0] = s.x * 0.25f;
        xs[r][d4 * 4 + 1] = s.y * 0.25f;
        xs[r][d4 * 4 + 2] = s.z * 0.25f;
        xs[r][d4 * 4 + 3] = s.w * 0.25f;
    }
    __syncthreads();
    float acc[16];
    #pragma unroll
    for (int r = 0; r < 16; ++r) acc[r] = 0.f;
    int c = tid;
    for (int d0 = 0; d0 < 256; d0 += 4) {
        float w0 = WT[(d0 + 0) * 256 + c];
        float w1 = WT[(d0 + 1) * 256 + c];
        float w2 = WT[(d0 + 2) * 256 + c];
        float w3 = WT[(d0 + 3) * 256 + c];
        #pragma unroll
        for (int r = 0; r < 16; ++r) {
            float4 xv = *(const float4*)&xs[r][d0];
            acc[r] = fmaf(xv.x, w0, acc[r]);
            acc[r] = fmaf(xv.y, w1, acc[r]);
            acc[r] = fmaf(xv.z, w2, acc[r]);
            acc[r] = fmaf(xv.w, w3, acc[r]);
        }
    }
    float bv = bias[c];
    #pragma unroll
    for (int r = 0; r < 16; ++r) {
        float qv = tanhf(acc[r] + bv);
        long long o = (long long)(row0 + r) * Dd + c;
        qf[o] = qv;
        qh[o] = f2h(qv);
    }
}

// ---------------- K3: att tile = q @ key^T (fp16 MFMA) + top-8/row cand + attw tile zero ----------------
// 1D grid of 4096 blocks, bijective XCD swizzle. Zero-fill interleaved into the K-loop (2 stores/step)
// so each store drains under a K-step's MFMA instead of at one lump vmcnt(0).
__global__ __launch_bounds__(256) void k_att(const unsigned short* __restrict__ qh,
                                             const unsigned short* __restrict__ kh,
                                             unsigned int* __restrict__ cand,
                                             float* __restrict__ attw) {
    // staging uses [0, 8192); C-tile: 128 rows x stride 136 shorts, slot-XOR swizzled
    __shared__ __align__(16) unsigned short smem[17408];
    int bid = blockIdx.x;
    int swz = (bid & 7) * 512 + (bid >> 3);     // XCD-contiguous chunks
    int bx = swz & 31;                          // col tile 0..31
    int by = swz >> 5;                          // row tile 0..127
    int tid = threadIdx.x;
    int lane = tid & 63, w = tid >> 6;
    int wr = w >> 1, wc = w & 1;
    long long row0 = (long long)by * 128;
    long long col0 = (long long)bx * 128;

    f32x4 acc[4][4];
    #pragma unroll
    for (int m = 0; m < 4; ++m)
        #pragma unroll
        for (int n = 0; n < 4; ++n) acc[m][n] = (f32x4){0.f, 0.f, 0.f, 0.f};

    int rr = lane >> 2;
    int sp = lane & 3;

    auto stage = [&](int k0) {
        #pragma unroll
        for (int t = 0; t < 2; ++t) {
            const unsigned short* src = t ? kh : qh;
            long long b0 = t ? col0 : row0;
            #pragma unroll
            for (int i = 0; i < 2; ++i) {
                int r = w * 32 + i * 16 + rr;
                int sl = sp ^ ((r >> 1) & 3);
                const unsigned short* g = src + (b0 + r) * 256 + k0 * 32 + sl * 8;
                unsigned short* l = smem + t * 4096 + (w * 32 + i * 16) * 32;
                gload_lds16(g, l);
            }
        }
    };

    // interleaved zero-fill helper: slot i in 0..15, covers 128x128 tile over 8 K-steps
    f32x4 zz = (f32x4){0.f, 0.f, 0.f, 0.f};
    auto zfill = [&](int i) {
        int s = i * 256 + tid;              // f32x4 slot 0..4095
        int r = s >> 5, c4 = s & 31;        // lanes 0-31 cover one row (512B contiguous)
        __builtin_nontemporal_store(zz, (f32x4*)(attw + (row0 + r) * Mm + col0 + c4 * 4));
    };

    stage(0);
    for (int k0 = 0; k0 < 8; ++k0) {
        __syncthreads();
        int lr = lane & 15, j = lane >> 4;
        f16x8 ah[4], bh[4];
        #pragma unroll
        for (int m = 0; m < 4; ++m) {
            int r = wr * 64 + m * 16 + lr;
            int off = r * 32 + ((j ^ ((r >> 1) & 3)) * 8);
            ah[m] = *(const f16x8*)(smem + off);
        }
        #pragma unroll
        for (int n = 0; n < 4; ++n) {
            int r = wc * 64 + n * 16 + lr;
            int off = r * 32 + ((j ^ ((r >> 1) & 3)) * 8);
            bh[n] = *(const f16x8*)(smem + 4096 + off);
        }
        if (k0 < 7) { __syncthreads(); stage(k0 + 1); }
        // issue 2 of the 16 zero-stores; they retire under this step's MFMA burst
        zfill(k0 * 2);
        zfill(k0 * 2 + 1);
        #pragma unroll
        for (int m = 0; m < 4; ++m)
            #pragma unroll
            for (int n = 0; n < 4; ++n)
                acc[m][n] = __builtin_amdgcn_mfma_f32_16x16x32_f16(ah[m], bh[n], acc[m][n], 0, 0, 0);
    }

    // ---- C fragments -> LDS f16 (stride 136, slot-XOR swizzle on 8-short slots) ----
    __syncthreads();   // all waves done reading staging LDS
    {
        int lr = lane & 15, j = lane >> 4;
        #pragma unroll
        for (int m = 0; m < 4; ++m)
            #pragma unroll
            for (int n = 0; n < 4; ++n) {
                int c = wc * 64 + n * 16 + lr;
                #pragma unroll
                for (int reg = 0; reg < 4; ++reg) {
                    int r = wr * 64 + m * 16 + j * 4 + reg;
                    int pc = (((c >> 3) ^ (r & 7)) << 3) | (c & 7);
                    smem[r * 136 + pc] = f2h(acc[m][n][reg]);
                }
            }
    }
    __syncthreads();

    // ---- per-row ranking: thread pair (2r, 2r+1) scans row r (64 cols each) ----
    {
        int r2 = tid >> 1;     // row 0..127
        int hf = tid & 1;      // half 0..1
        unsigned int v[8];
        #pragma unroll
        for (int s = 0; s < 8; ++s) v[s] = 0u;

        #pragma unroll
        for (int t8 = 0; t8 < 8; ++t8) {
            int slot = hf * 8 + t8;
            short8 x8 = *(const short8*)(smem + r2 * 136 + ((slot ^ (r2 & 7)) << 3));
            int gc0 = (int)col0 + slot * 8;
            #pragma unroll
            for (int jj = 0; jj < 8; ++jj) {
                unsigned int b = (unsigned short)x8[jj];
                unsigned int sr = (unsigned)((int)(b << 16) >> 31);
                unsigned int mono = b ^ ((sr >> 17) | 0x8000u);
                unsigned int keyv = (mono << 16) | (unsigned)(4095 - (gc0 + jj));
                if (keyv > v[7]) {
                    unsigned int x = keyv;
                    #pragma unroll
                    for (int s = 0; s < 8; ++s) {
                        unsigned int hi = v[s] > x ? v[s] : x;
                        unsigned int lo = v[s] > x ? x : v[s];
                        v[s] = hi; x = lo;
                    }
                }
            }
        }
        // merge partner halves: top-8 of union (bitonic select), sets identical in both lanes
        unsigned int nv[8];
        #pragma unroll
        for (int s = 0; s < 8; ++s) {
            unsigned int pv = (unsigned)__shfl_xor((int)v[7 - s], 1);
            nv[s] = v[s] > pv ? v[s] : pv;
        }
        if (hf == 0) {
            // cand[row][tile][8] layout: contiguous per-row reads in k_final2
            unsigned int* dst = cand + ((row0 + r2) * 32 + bx) * 8;
            uint4 a = make_uint4(nv[0], nv[1], nv[2], nv[3]);
            uint4 bq = make_uint4(nv[4], nv[5], nv[6], nv[7]);
            *(uint4*)dst = a;
            *(uint4*)(dst + 4) = bq;
        }
    }
}

// ---------------- K4: gather 256 cand keys -> top-16 -> fp64 refine -> top-8 + outputs ----------------
// attw rows were zeroed by k_att; only sparse inserts here.
__global__ __launch_bounds__(256) void k_final2(const unsigned int* __restrict__ cand,
                                                const float* __restrict__ qf,
                                                const float* __restrict__ key,
                                                const float* __restrict__ mem,
                                                const float* __restrict__ mlab,
                                                float* __restrict__ gate,
                                                float* __restrict__ memr,
                                                float* __restrict__ labr,
                                                float* __restrict__ attw) {
    int tid = threadIdx.x;
    int lane = tid & 63;
    long long row = (long long)blockIdx.x * 4 + (tid >> 6);

    // ---- contiguous row read: lane loads uint4 at row*256 + lane*4 ----
    uint4 kk = *(const uint4*)(cand + row * 256 + lane * 4);

    unsigned int v[4];
    #pragma unroll
    for (int s = 0; s < 4; ++s) v[s] = 0u;
    {
        unsigned int ins[4] = {kk.x, kk.y, kk.z, kk.w};
        #pragma unroll
        for (int i = 0; i < 4; ++i) {
            unsigned int x = ins[i];
            #pragma unroll
            for (int s = 0; s < 4; ++s) {
                unsigned int hi = v[s] > x ? v[s] : x;
                unsigned int lo = v[s] > x ? x : v[s];
                v[s] = hi; x = lo;
            }
        }
    }

    // ---- extract global top-16 via wave-max pops ----
    unsigned int sk[KC];
    #pragma unroll
    for (int k = 0; k < KC; ++k) {
        unsigned int bv = v[0];
        #pragma unroll
        for (int d = 1; d < 64; d <<= 1) {
            unsigned int ov = (unsigned)__shfl_xor((int)bv, d);
            bv = bv > ov ? bv : ov;
        }
        sk[k] = bv;
        bool won = (v[0] == bv);
        v[0] = won ? v[1] : v[0];
        v[1] = won ? v[2] : v[1];
        v[2] = won ? v[3] : v[2];
        v[3] = won ? 0u : v[3];
    }

    int civ[KC];
    #pragma unroll
    for (int s = 0; s < KC; ++s) civ[s] = 4095 - (int)(sk[s] & 0xFFFu);

    // ---- refine: candidate c = lane&15, slice g = lane>>4, fp64 dot ----
    int c = lane & 15, g = lane >> 4;
    int cidx = civ[0];
    #pragma unroll
    for (int s = 1; s < KC; ++s) cidx = (c == s) ? civ[s] : cidx;
    const float* qrow = qf + row * Dd;
    const float* krow = key + (long long)cidx * Dd;
    double dacc = 0.0;
    #pragma unroll
    for (int i = 0; i < 16; ++i) {
        float4 qv = *(const float4*)(qrow + g * 64 + i * 4);
        float4 kv = *(const float4*)(krow + g * 64 + i * 4);
        dacc = fma((double)qv.x, (double)kv.x, dacc);
        dacc = fma((double)qv.y, (double)kv.y, dacc);
        dacc = fma((double)qv.z, (double)kv.z, dacc);
        dacc = fma((double)qv.w, (double)kv.w, dacc);
    }
    dacc += __shfl_xor(dacc, 16);
    dacc += __shfl_xor(dacc, 32);
    float rvf = (float)dacc;

    float cv[KC];
    #pragma unroll
    for (int s = 0; s < KC; ++s) cv[s] = __shfl(rvf, s);

    // ---- all-pairs rank on (refined value desc, idx asc); selected = rank<8 ----
    unsigned int m32[KC];
    #pragma unroll
    for (int s = 0; s < KC; ++s) {
        unsigned int fb = __float_as_uint(cv[s]);
        m32[s] = fb ^ ((unsigned)((int)fb >> 31) | 0x80000000u);
    }
    bool sel[KC];
    #pragma unroll
    for (int s = 0; s < KC; ++s) {
        int r = 0;
        #pragma unroll
        for (int t = 0; t < KC; ++t) {
            if (t != s) {
                bool gt = (m32[t] > m32[s]) || (m32[t] == m32[s] && civ[t] < civ[s]);
                r += gt ? 1 : 0;
            }
        }
        sel[s] = (r < KSEL);
    }

    // ---- softmax over selected ----
    float mx = cv[0];
    #pragma unroll
    for (int s = 1; s < KC; ++s) mx = fmaxf(mx, cv[s]);
    float p[KC]; float z = 0.f;
    #pragma unroll
    for (int s = 0; s < KC; ++s) { p[s] = sel[s] ? expf(cv[s] - mx) : 0.f; z += p[s]; }
    float inv = 1.f / z;
    #pragma unroll
    for (int s = 0; s < KC; ++s) p[s] *= inv;

    // ---- mem_retrieved (reads mem rows; overwrites q row after full read) ----
    {
        float4 a = make_float4(0.f, 0.f, 0.f, 0.f);
        #pragma unroll
        for (int s = 0; s < KC; ++s) {
            if (sel[s]) {
                const float4 mv = *(const float4*)(mem + (long long)civ[s] * Dd + lane * 4);
                a.x = fmaf(p[s], mv.x, a.x); a.y = fmaf(p[s], mv.y, a.y);
                a.z = fmaf(p[s], mv.z, a.z); a.w = fmaf(p[s], mv.w, a.w);
            }
        }
        *(float4*)(memr + row * Dd + lane * 4) = a;
    }

    if (lane < Ee) {
        float s8 = 0.f;
        #pragma unroll
        for (int s = 0; s < KC; ++s)
            if (sel[s]) s8 = fmaf(p[s], mlab[(long long)civ[s] * Ee + lane], s8);
        gate[row * Ee + lane] = s8;
        labr[row * Ee + lane] = s8;
    }

    // ---- sparse insert into pre-zeroed attw row ----
    if (lane < KC) {
        float myp = p[0]; int myi = civ[0];
        #pragma unroll
        for (int s = 1; s < KC; ++s) {
            myp = (lane == s) ? p[s] : myp;
            myi = (lane == s) ? civ[s] : myi;
        }
        attw[row * Mm + myi] = myp;   // unselected lanes write 0.0 (true value there is 0.0)
    }
}

extern "C" void kernel_launch(void* const* d_in, const int* in_sizes, int n_in,
                              void* d_out, int out_size, void* d_ws, size_t ws_size,
                              hipStream_t stream) {
    const float* prop = (const float*)d_in[0];
    const float* W    = (const float*)d_in[2];
    const float* bias = (const float*)d_in[3];
    const float* key  = (const float*)d_in[4];
    const float* mem  = (const float*)d_in[5];
    const float* wg   = (const float*)d_in[6];

    float* out  = (float*)d_out;
    float* gate = out + O_GATE;
    float* memr = out + O_MEMR;
    float* labr = out + O_LABR;
    float* mlab = out + O_MLAB;
    float* attw = out + O_ATTW;

    char* ws = (char*)d_ws;
    float*          WT   = (float*)(ws + WS_WT);
    unsigned short* kh   = (unsigned short*)(ws + WS_KH);
    unsigned int*   cand = (unsigned int*)(ws + WS_CAND);
    unsigned short* qh   = (unsigned short*)(ws + WS_QH);
    float*          qf   = memr;   // fp32 q in memr output region (dead before overwrite)

    k_prep<<<4368, 256, 0, stream>>>(W, WT, key, kh, mem, wg, mlab);
    k_q<<<ROWS / 16, 256, 0, stream>>>(prop, WT, bias, qf, qh);
    k_att<<<4096, 256, 0, stream>>>(qh, kh, cand, attw);
    k_final2<<<ROWS / 4, 256, 0, stream>>>(cand, qf, key, mem, mlab, gate, memr, labr, attw);
}

// Round 14
// 248.050 us; speedup vs baseline: 1.0441x; 1.0441x over previous
//
#include <hip/hip_runtime.h>
#include <hip/hip_fp16.h>
#include <math.h>

#define Bb 8
#define Tt 4
#define Nn 2048
#define Dd 256
#define Mm 4096
#define Ee 8
#define ROWS (Bb*Nn)   // 16384
#define KSEL 8
#define KC 16          // ranking candidates

// output offsets (floats)
#define O_GATE 0LL
#define O_MEMR 131072LL
#define O_LABR 4325376LL
#define O_MLAB 4456448LL
#define O_ATTW 4489216LL

// ws layout (bytes)
#define WS_WT    0LL            // 256 KB fp32 WT
#define WS_KH    262144LL       // 2 MB f16 key
#define WS_CAND  16777216LL     // 16.8 MB u32 cand[32][16384][8]
#define WS_QH    150994944LL    // 8 MB f16 q

typedef float f32x4 __attribute__((ext_vector_type(4)));
typedef short short8 __attribute__((ext_vector_type(8)));
typedef _Float16 f16x8 __attribute__((ext_vector_type(8)));

__device__ __forceinline__ unsigned short f2h(float x) {
    __half h = __float2half(x);
    return *reinterpret_cast<unsigned short*>(&h);
}

__device__ __forceinline__ void gload_lds16(const void* g, void* l) {
    __builtin_amdgcn_global_load_lds(
        (const __attribute__((address_space(1))) unsigned int*)g,
        (__attribute__((address_space(3))) unsigned int*)l,
        16, 0, 0);
}

// ---------------- K0: prep (transpose W | key->f16 | mem_label) ----------------
// grid = 256 + 4096 + 16 = 4368 blocks
__global__ __launch_bounds__(256) void k_prep(const float* __restrict__ W, float* __restrict__ WT,
                                              const float* __restrict__ key, unsigned short* __restrict__ kh,
                                              const float* __restrict__ mem, const float* __restrict__ wg,
                                              float* __restrict__ mlab) {
    int b = blockIdx.x, tid = threadIdx.x;
    if (b < 256) {
        int i = b * 256 + tid;
        int r = i >> 8, c = i & 255;
        WT[c * 256 + r] = W[r * 256 + c];
    } else if (b < 256 + 4096) {
        int idx = (b - 256) * 256 + tid;     // covers all Mm*Dd = 1048576
        kh[idx] = f2h(key[idx]);
    } else {
        int m = (b - 4352) * 256 + tid;
        if (m < Mm) {
            float acc[Ee];
            #pragma unroll
            for (int e = 0; e < Ee; ++e) acc[e] = 0.f;
            const float* mr = mem + (long long)m * Dd;
            for (int d = 0; d < Dd; ++d) {
                float mv = mr[d];
                #pragma unroll
                for (int e = 0; e < Ee; ++e) acc[e] = fmaf(mv, wg[d * Ee + e], acc[e]);
            }
            float mx = acc[0];
            #pragma unroll
            for (int e = 1; e < Ee; ++e) mx = fmaxf(mx, acc[e]);
            float z = 0.f;
            #pragma unroll
            for (int e = 0; e < Ee; ++e) { acc[e] = expf(acc[e] - mx); z += acc[e]; }
            float inv = 1.f / z;
            #pragma unroll
            for (int e = 0; e < Ee; ++e) mlab[(long long)m * Ee + e] = acc[e] * inv;
        }
    }
}

// ---------------- K1: x = mean_T(prop); q = tanh(x @ W^T + b) -> f32 + f16 ----------------
__global__ __launch_bounds__(256) void k_q(const float* __restrict__ prop,
                                           const float* __restrict__ WT,
                                           const float* __restrict__ bias,
                                           float* __restrict__ qf,
                                           unsigned short* __restrict__ qh) {
    __shared__ float xs[16][256];
    int tid = threadIdx.x;
    int row0 = blockIdx.x * 16;
    // float4 prop loads: 4 rows per pass, thread -> (row = pass*4 + tid>>6, d4 = tid&63)
    #pragma unroll
    for (int pass = 0; pass < 4; ++pass) {
        int r = pass * 4 + (tid >> 6);
        int d4 = tid & 63;
        int row = row0 + r;
        int b = row >> 11;
        int n = row & 2047;
        const float4* p = (const float4*)(prop + ((long long)(b * Tt) * Nn + n) * Dd) + d4;
        float4 s = make_float4(0.f, 0.f, 0.f, 0.f);
        #pragma unroll
        for (int t = 0; t < Tt; ++t) {
            float4 v = p[(long long)t * Nn * Dd / 4];
            s.x += v.x; s.y += v.y; s.z += v.z; s.w += v.w;
        }
        xs[r][d4 * 4 + 0] = s.x * 0.25f;
        xs[r][d4 * 4 + 1] = s.y * 0.25f;
        xs[r][d4 * 4 + 2] = s.z * 0.25f;
        xs[r][d4 * 4 + 3] = s.w * 0.25f;
    }
    __syncthreads();
    float acc[16];
    #pragma unroll
    for (int r = 0; r < 16; ++r) acc[r] = 0.f;
    int c = tid;
    for (int d = 0; d < 256; ++d) {
        float wv = WT[d * 256 + c];
        #pragma unroll
        for (int r = 0; r < 16; ++r) acc[r] = fmaf(xs[r][d], wv, acc[r]);
    }
    float bv = bias[c];
    #pragma unroll
    for (int r = 0; r < 16; ++r) {
        float qv = tanhf(acc[r] + bv);
        long long o = (long long)(row0 + r) * Dd + c;
        qf[o] = qv;
        qh[o] = f2h(qv);
    }
}

// ---------------- K3: att tile = q @ key^T (fp16 MFMA) + top-8/row cand + attw tile zero ----------------
// 1D grid of 4096 blocks, bijective XCD swizzle (4096 % 8 == 0). No att matrix materialized.
__global__ __launch_bounds__(256) void k_att(const unsigned short* __restrict__ qh,
                                             const unsigned short* __restrict__ kh,
                                             unsigned int* __restrict__ cand,
                                             float* __restrict__ attw) {
    // staging uses [0, 8192); C-tile: 128 rows x stride 136 shorts, slot-XOR swizzled
    __shared__ __align__(16) unsigned short smem[17408];
    int bid = blockIdx.x;
    int swz = (bid & 7) * 512 + (bid >> 3);     // XCD-contiguous chunks
    int bx = swz & 31;                          // col tile 0..31
    int by = swz >> 5;                          // row tile 0..127
    int tid = threadIdx.x;
    int lane = tid & 63, w = tid >> 6;
    int wr = w >> 1, wc = w & 1;
    long long row0 = (long long)by * 128;
    long long col0 = (long long)bx * 128;

    f32x4 acc[4][4];
    #pragma unroll
    for (int m = 0; m < 4; ++m)
        #pragma unroll
        for (int n = 0; n < 4; ++n) acc[m][n] = (f32x4){0.f, 0.f, 0.f, 0.f};

    int rr = lane >> 2;
    int sp = lane & 3;

    auto stage = [&](int k0) {
        #pragma unroll
        for (int t = 0; t < 2; ++t) {
            const unsigned short* src = t ? kh : qh;
            long long b0 = t ? col0 : row0;
            #pragma unroll
            for (int i = 0; i < 2; ++i) {
                int r = w * 32 + i * 16 + rr;
                int sl = sp ^ ((r >> 1) & 3);
                const unsigned short* g = src + (b0 + r) * 256 + k0 * 32 + sl * 8;
                unsigned short* l = smem + t * 4096 + (w * 32 + i * 16) * 32;
                gload_lds16(g, l);
            }
        }
    };

    stage(0);
    for (int k0 = 0; k0 < 8; ++k0) {
        __syncthreads();
        int lr = lane & 15, j = lane >> 4;
        f16x8 ah[4], bh[4];
        #pragma unroll
        for (int m = 0; m < 4; ++m) {
            int r = wr * 64 + m * 16 + lr;
            int off = r * 32 + ((j ^ ((r >> 1) & 3)) * 8);
            ah[m] = *(const f16x8*)(smem + off);
        }
        #pragma unroll
        for (int n = 0; n < 4; ++n) {
            int r = wc * 64 + n * 16 + lr;
            int off = r * 32 + ((j ^ ((r >> 1) & 3)) * 8);
            bh[n] = *(const f16x8*)(smem + 4096 + off);
        }
        #pragma unroll
        for (int m = 0; m < 4; ++m)
            #pragma unroll
            for (int n = 0; n < 4; ++n)
                acc[m][n] = __builtin_amdgcn_mfma_f32_16x16x32_f16(ah[m], bh[n], acc[m][n], 0, 0, 0);
        if (k0 < 7) { __syncthreads(); stage(k0 + 1); }
    }

    // ---- NT zero-fill of this block's 128x128 attw tile (post-GEMM, pre-epilogue: R11 placement) ----
    {
        f32x4 zz = (f32x4){0.f, 0.f, 0.f, 0.f};
        #pragma unroll
        for (int i = 0; i < 16; ++i) {
            int s = i * 256 + tid;              // f32x4 slot 0..4095
            int r = s >> 5, c4 = s & 31;        // lanes 0-31 cover one row (512B contiguous)
            __builtin_nontemporal_store(zz, (f32x4*)(attw + (row0 + r) * Mm + col0 + c4 * 4));
        }
    }

    // ---- C fragments -> LDS f16 (stride 136, slot-XOR swizzle on 8-short slots) ----
    __syncthreads();   // all waves done reading staging LDS
    {
        int lr = lane & 15, j = lane >> 4;
        #pragma unroll
        for (int m = 0; m < 4; ++m)
            #pragma unroll
            for (int n = 0; n < 4; ++n) {
                int c = wc * 64 + n * 16 + lr;
                #pragma unroll
                for (int reg = 0; reg < 4; ++reg) {
                    int r = wr * 64 + m * 16 + j * 4 + reg;
                    int pc = (((c >> 3) ^ (r & 7)) << 3) | (c & 7);
                    smem[r * 136 + pc] = f2h(acc[m][n][reg]);
                }
            }
    }
    __syncthreads();

    // ---- per-row ranking: thread pair (2r, 2r+1) scans row r (64 cols each) ----
    {
        int r2 = tid >> 1;     // row 0..127
        int hf = tid & 1;      // half 0..1
        unsigned int v[8];
        #pragma unroll
        for (int s = 0; s < 8; ++s) v[s] = 0u;

        #pragma unroll
        for (int t8 = 0; t8 < 8; ++t8) {
            int slot = hf * 8 + t8;
            short8 x8 = *(const short8*)(smem + r2 * 136 + ((slot ^ (r2 & 7)) << 3));
            int gc0 = (int)col0 + slot * 8;
            #pragma unroll
            for (int jj = 0; jj < 8; ++jj) {
                unsigned int b = (unsigned short)x8[jj];
                unsigned int sr = (unsigned)((int)(b << 16) >> 31);
                unsigned int mono = b ^ ((sr >> 17) | 0x8000u);
                unsigned int keyv = (mono << 16) | (unsigned)(4095 - (gc0 + jj));
                if (keyv > v[7]) {
                    unsigned int x = keyv;
                    #pragma unroll
                    for (int s = 0; s < 8; ++s) {
                        unsigned int hi = v[s] > x ? v[s] : x;
                        unsigned int lo = v[s] > x ? x : v[s];
                        v[s] = hi; x = lo;
                    }
                }
            }
        }
        // merge partner halves: top-8 of union (bitonic select), sets identical in both lanes
        unsigned int nv[8];
        #pragma unroll
        for (int s = 0; s < 8; ++s) {
            unsigned int pv = (unsigned)__shfl_xor((int)v[7 - s], 1);
            nv[s] = v[s] > pv ? v[s] : pv;
        }
        if (hf == 0) {
            unsigned int* dst = cand + ((long long)bx * ROWS + row0 + r2) * 8;
            uint4 a = make_uint4(nv[0], nv[1], nv[2], nv[3]);
            uint4 bq = make_uint4(nv[4], nv[5], nv[6], nv[7]);
            *(uint4*)dst = a;
            *(uint4*)(dst + 4) = bq;
        }
    }
}

// ---------------- K4: gather 256 cand keys -> top-16 -> fp64 refine -> top-8 + outputs ----------------
// attw rows were zeroed by k_att; only sparse inserts here.
__global__ __launch_bounds__(256) void k_final2(const unsigned int* __restrict__ cand,
                                                const float* __restrict__ qf,
                                                const float* __restrict__ key,
                                                const float* __restrict__ mem,
                                                const float* __restrict__ mlab,
                                                float* __restrict__ gate,
                                                float* __restrict__ memr,
                                                float* __restrict__ labr,
                                                float* __restrict__ attw) {
    int tid = threadIdx.x;
    int lane = tid & 63;
    long long row = (long long)blockIdx.x * 4 + (tid >> 6);

    // ---- each lane loads 4 keys: tile = lane>>1, half (lane&1)*4 ----
    int tl = lane >> 1, of = (lane & 1) * 4;
    uint4 kk = *(const uint4*)(cand + ((long long)tl * ROWS + row) * 8 + of);

    unsigned int v[4];
    #pragma unroll
    for (int s = 0; s < 4; ++s) v[s] = 0u;
    {
        unsigned int ins[4] = {kk.x, kk.y, kk.z, kk.w};
        #pragma unroll
        for (int i = 0; i < 4; ++i) {
            unsigned int x = ins[i];
            #pragma unroll
            for (int s = 0; s < 4; ++s) {
                unsigned int hi = v[s] > x ? v[s] : x;
                unsigned int lo = v[s] > x ? x : v[s];
                v[s] = hi; x = lo;
            }
        }
    }

    // ---- extract global top-16 via wave-max pops ----
    unsigned int sk[KC];
    #pragma unroll
    for (int k = 0; k < KC; ++k) {
        unsigned int bv = v[0];
        #pragma unroll
        for (int d = 1; d < 64; d <<= 1) {
            unsigned int ov = (unsigned)__shfl_xor((int)bv, d);
            bv = bv > ov ? bv : ov;
        }
        sk[k] = bv;
        bool won = (v[0] == bv);
        v[0] = won ? v[1] : v[0];
        v[1] = won ? v[2] : v[1];
        v[2] = won ? v[3] : v[2];
        v[3] = won ? 0u : v[3];
    }

    int civ[KC];
    #pragma unroll
    for (int s = 0; s < KC; ++s) civ[s] = 4095 - (int)(sk[s] & 0xFFFu);

    // ---- refine: candidate c = lane&15, slice g = lane>>4, fp64 dot ----
    int c = lane & 15, g = lane >> 4;
    int cidx = civ[0];
    #pragma unroll
    for (int s = 1; s < KC; ++s) cidx = (c == s) ? civ[s] : cidx;
    const float* qrow = qf + row * Dd;
    const float* krow = key + (long long)cidx * Dd;
    double dacc = 0.0;
    #pragma unroll
    for (int i = 0; i < 16; ++i) {
        float4 qv = *(const float4*)(qrow + g * 64 + i * 4);
        float4 kv = *(const float4*)(krow + g * 64 + i * 4);
        dacc = fma((double)qv.x, (double)kv.x, dacc);
        dacc = fma((double)qv.y, (double)kv.y, dacc);
        dacc = fma((double)qv.z, (double)kv.z, dacc);
        dacc = fma((double)qv.w, (double)kv.w, dacc);
    }
    dacc += __shfl_xor(dacc, 16);
    dacc += __shfl_xor(dacc, 32);
    float rvf = (float)dacc;

    float cv[KC];
    #pragma unroll
    for (int s = 0; s < KC; ++s) cv[s] = __shfl(rvf, s);

    // ---- all-pairs rank on (refined value desc, idx asc); selected = rank<8 ----
    unsigned int m32[KC];
    #pragma unroll
    for (int s = 0; s < KC; ++s) {
        unsigned int fb = __float_as_uint(cv[s]);
        m32[s] = fb ^ ((unsigned)((int)fb >> 31) | 0x80000000u);
    }
    bool sel[KC];
    #pragma unroll
    for (int s = 0; s < KC; ++s) {
        int r = 0;
        #pragma unroll
        for (int t = 0; t < KC; ++t) {
            if (t != s) {
                bool gt = (m32[t] > m32[s]) || (m32[t] == m32[s] && civ[t] < civ[s]);
                r += gt ? 1 : 0;
            }
        }
        sel[s] = (r < KSEL);
    }

    // ---- softmax over selected ----
    float mx = cv[0];
    #pragma unroll
    for (int s = 1; s < KC; ++s) mx = fmaxf(mx, cv[s]);
    float p[KC]; float z = 0.f;
    #pragma unroll
    for (int s = 0; s < KC; ++s) { p[s] = sel[s] ? expf(cv[s] - mx) : 0.f; z += p[s]; }
    float inv = 1.f / z;
    #pragma unroll
    for (int s = 0; s < KC; ++s) p[s] *= inv;

    // ---- mem_retrieved (reads mem rows; overwrites q row after full read) ----
    {
        float4 a = make_float4(0.f, 0.f, 0.f, 0.f);
        #pragma unroll
        for (int s = 0; s < KC; ++s) {
            if (sel[s]) {
                const float4 mv = *(const float4*)(mem + (long long)civ[s] * Dd + lane * 4);
                a.x = fmaf(p[s], mv.x, a.x); a.y = fmaf(p[s], mv.y, a.y);
                a.z = fmaf(p[s], mv.z, a.z); a.w = fmaf(p[s], mv.w, a.w);
            }
        }
        *(float4*)(memr + row * Dd + lane * 4) = a;
    }

    if (lane < Ee) {
        float s8 = 0.f;
        #pragma unroll
        for (int s = 0; s < KC; ++s)
            if (sel[s]) s8 = fmaf(p[s], mlab[(long long)civ[s] * Ee + lane], s8);
        gate[row * Ee + lane] = s8;
        labr[row * Ee + lane] = s8;
    }

    // ---- sparse insert into pre-zeroed attw row ----
    if (lane < KC) {
        float myp = p[0]; int myi = civ[0];
        #pragma unroll
        for (int s = 1; s < KC; ++s) {
            myp = (lane == s) ? p[s] : myp;
            myi = (lane == s) ? civ[s] : myi;
        }
        attw[row * Mm + myi] = myp;   // unselected lanes write 0.0 (true value there is 0.0)
    }
}

extern "C" void kernel_launch(void* const* d_in, const int* in_sizes, int n_in,
                              void* d_out, int out_size, void* d_ws, size_t ws_size,
                              hipStream_t stream) {
    const float* prop = (const float*)d_in[0];
    const float* W    = (const float*)d_in[2];
    const float* bias = (const float*)d_in[3];
    const float* key  = (const float*)d_in[4];
    const float* mem  = (const float*)d_in[5];
    const float* wg   = (const float*)d_in[6];

    float* out  = (float*)d_out;
    float* gate = out + O_GATE;
    float* memr = out + O_MEMR;
    float* labr = out + O_LABR;
    float* mlab = out + O_MLAB;
    float* attw = out + O_ATTW;

    char* ws = (char*)d_ws;
    float*          WT   = (float*)(ws + WS_WT);
    unsigned short* kh   = (unsigned short*)(ws + WS_KH);
    unsigned int*   cand = (unsigned int*)(ws + WS_CAND);
    unsigned short* qh   = (unsigned short*)(ws + WS_QH);
    float*          qf   = memr;   // fp32 q in memr output region (dead before overwrite)

    k_prep<<<4368, 256, 0, stream>>>(W, WT, key, kh, mem, wg, mlab);
    k_q<<<ROWS / 16, 256, 0, stream>>>(prop, WT, bias, qf, qh);
    k_att<<<4096, 256, 0, stream>>>(qh, kh, cand, attw);
    k_final2<<<ROWS / 4, 256, 0, stream>>>(cand, qf, key, mem, mlab, gate, memr, labr, attw);
}